// Round 1
// baseline (3452.320 us; speedup 1.0000x reference)
//
#include <hip/hip_runtime.h>
#include <math.h>

#define BATCH 32
#define DEPTH 12
#define DIM 768
#define HEADS 12
#define MLP_DIM 3072
#define PATCH 16
#define GRIDSZ 14
#define NCLS 1000
#define N_TOK 197
#define HD 64
#define NPATCH 196

typedef __attribute__((ext_vector_type(8))) short short8;
typedef __attribute__((ext_vector_type(4))) float floatx4;
typedef unsigned short ushort;

__device__ inline float us2f(ushort u) {
    union { unsigned int i; float f; } c; c.i = ((unsigned int)u) << 16; return c.f;
}
__device__ inline ushort f2bf(float f) {
    unsigned int x = __float_as_uint(f);
    unsigned int r = (x + 0x7fffu + ((x >> 16) & 1u)) >> 16;
    return (ushort)r;
}

#define GAS __attribute__((address_space(1)))
#define LAS __attribute__((address_space(3)))
__device__ inline void async_copy16(const void* g, void* l) {
    __builtin_amdgcn_global_load_lds((const GAS void*)g, (LAS void*)l, 16, 0, 0);
}

// ---------------------------------------------------------------------------
__global__ __launch_bounds__(256) void im2col_kernel(const float* __restrict__ x,
                                                     ushort* __restrict__ patches) {
    int idx = blockIdx.x * 256 + threadIdx.x;
    const int total = BATCH * NPATCH * DIM;
    if (idx >= total) return;
    int e = idx % DIM;
    int n = (idx / DIM) % NPATCH;
    int b = idx / (DIM * NPATCH);
    int c = e / (PATCH * PATCH);
    int r = e % (PATCH * PATCH);
    int py = r / PATCH, px = r % PATCH;
    int gy = n / GRIDSZ, gx = n % GRIDSZ;
    size_t xi = (((size_t)(b * 3 + c) * 224 + gy * PATCH + py)) * 224 + gx * PATCH + px;
    patches[idx] = f2bf(x[xi]);
}

// ---------------------------------------------------------------------------
__global__ __launch_bounds__(256) void assemble_kernel(const float* __restrict__ patchout,
                                                       const float* __restrict__ cls,
                                                       const float* __restrict__ pos,
                                                       float* __restrict__ t) {
    int idx = blockIdx.x * 256 + threadIdx.x;
    const int total = BATCH * N_TOK * DIM;
    if (idx >= total) return;
    int d = idx % DIM;
    int n = (idx / DIM) % N_TOK;
    int b = idx / (DIM * N_TOK);
    float v = (n == 0) ? cls[d] : patchout[((size_t)b * NPATCH + (n - 1)) * DIM + d];
    t[idx] = v + pos[n * DIM + d];
}

// ---------------------------------------------------------------------------
// LayerNorm, wave-per-row: block = 4 waves = 4 rows. 768 = 64 lanes * 12.
// ---------------------------------------------------------------------------
__global__ __launch_bounds__(256) void lnw_kernel(const float* __restrict__ x,
                                                  const float* __restrict__ g,
                                                  const float* __restrict__ bta,
                                                  ushort* __restrict__ out,
                                                  int rows, int in_stride, int out_stride) {
    int w = threadIdx.x >> 6, l = threadIdx.x & 63;
    int row = blockIdx.x * 4 + w;
    if (row >= rows) return;
    const float* xr = x + (size_t)row * in_stride;
    float4 v[3];
    float s = 0.0f, s2 = 0.0f;
#pragma unroll
    for (int c = 0; c < 3; c++) {
        v[c] = *(const float4*)(xr + c * 256 + l * 4);
        s  += v[c].x + v[c].y + v[c].z + v[c].w;
        s2 += v[c].x * v[c].x + v[c].y * v[c].y + v[c].z * v[c].z + v[c].w * v[c].w;
    }
#pragma unroll
    for (int off = 32; off; off >>= 1) { s += __shfl_xor(s, off); s2 += __shfl_xor(s2, off); }
    float mean = s * (1.0f / DIM);
    float inv = rsqrtf(s2 * (1.0f / DIM) - mean * mean + 1e-6f);
    ushort* orow = out + (size_t)row * out_stride;
#pragma unroll
    for (int c = 0; c < 3; c++) {
        float4 gg = *(const float4*)(g + c * 256 + l * 4);
        float4 bb = *(const float4*)(bta + c * 256 + l * 4);
        ushort4 o4;
        o4.x = f2bf((v[c].x - mean) * inv * gg.x + bb.x);
        o4.y = f2bf((v[c].y - mean) * inv * gg.y + bb.y);
        o4.z = f2bf((v[c].z - mean) * inv * gg.z + bb.z);
        o4.w = f2bf((v[c].w - mean) * inv * gg.w + bb.w);
        *(ushort4*)(orow + c * 256 + l * 4) = o4;
    }
}

// ---------------------------------------------------------------------------
// Bounded transpose (pre-loop: patch_w, head_w). in KxN -> out NxK bf16.
// ---------------------------------------------------------------------------
__global__ __launch_bounds__(256) void transpose_bf16_kernel(const float* __restrict__ in,
                                                             ushort* __restrict__ out,
                                                             int K, int N) {
    __shared__ float tile[32][33];
    int n0 = blockIdx.x * 32, k0 = blockIdx.y * 32;
    int tx = threadIdx.x;
    int ty = threadIdx.y;
    for (int r = ty; r < 32; r += 8) {
        int k = k0 + r, n = n0 + tx;
        tile[r][tx] = (k < K && n < N) ? in[(size_t)k * N + n] : 0.0f;
    }
    __syncthreads();
    for (int r = ty; r < 32; r += 8) {
        int n = n0 + r, k = k0 + tx;
        if (n < N && k < K) out[(size_t)n * K + k] = f2bf(tile[tx][r]);
    }
}

// ---------------------------------------------------------------------------
// Batched per-layer transpose of the 4 weight mats (all dims %32==0).
// tiles: qkv 72x24=1728 | proj 24x24=576 | fc1 96x24=2304 | fc2 24x96=2304
// ---------------------------------------------------------------------------
__global__ __launch_bounds__(256) void transpose4_kernel(
    const float* __restrict__ w0, const float* __restrict__ w1,
    const float* __restrict__ w2, const float* __restrict__ w3,
    ushort* __restrict__ o0, ushort* __restrict__ o1,
    ushort* __restrict__ o2, ushort* __restrict__ o3) {
    __shared__ float tile[32][33];
    int bid = blockIdx.x;
    const float* in; ushort* out; int K, N, nx, tl;
    if (bid < 1728)      { in = w0; out = o0; K = 768;  N = 2304; nx = 72; tl = bid; }
    else if (bid < 2304) { in = w1; out = o1; K = 768;  N = 768;  nx = 24; tl = bid - 1728; }
    else if (bid < 4608) { in = w2; out = o2; K = 768;  N = 3072; nx = 96; tl = bid - 2304; }
    else                 { in = w3; out = o3; K = 3072; N = 768;  nx = 24; tl = bid - 4608; }
    int n0 = (tl % nx) * 32, k0 = (tl / nx) * 32;
    int tx = threadIdx.x, ty = threadIdx.y;
    for (int r = ty; r < 32; r += 8)
        tile[r][tx] = in[(size_t)(k0 + r) * N + n0 + tx];
    __syncthreads();
    for (int r = ty; r < 32; r += 8)
        out[(size_t)(n0 + r) * K + k0 + tx] = f2bf(tile[tx][r]);
}

// ---------------------------------------------------------------------------
// bf16 MFMA GEMM: BMx128x64 tiles (BM=128 or 64), 4 waves, 16x16x32 MFMA.
// XOR-swizzled LDS chunks (conflict-free ds_read_b128), GROUP_M=8 block
// swizzle for L2 locality. Wt is NxK (row n = col n of W).
//
// Round-4: 2-phase double-buffered pipeline with counted vmcnt (T3-minimum).
// stage(t+1) is issued BEFORE waiting on tile t; s_waitcnt vmcnt(NL) keeps
// the t+1 loads in flight across the raw s_barrier (a __syncthreads here
// would drain vmcnt(0) and expose full global->LDS latency every K-step,
// which was the measured 15%-MfmaUtil bottleneck).
// ---------------------------------------------------------------------------
template <int BM, int GELU, int RES, int WF32, int WBF16>
__global__ __launch_bounds__(256) void gemm_bf16_mfma(
    const ushort* __restrict__ A, const ushort* __restrict__ Wt,
    const float* __restrict__ bias, const float* __restrict__ res,
    float* __restrict__ Cf, ushort* __restrict__ Cb,
    int M, int N, int K) {
    constexpr int WN = (BM == 128) ? 2 : 4;   // waves along N
    constexpr int FN = (BM == 128) ? 4 : 2;   // 16-col frags per wave
    constexpr int AROWS = BM / 4;             // A rows staged per wave
    constexpr int ABUF = BM * 64;             // shorts per A buffer
    constexpr int BBUF = 128 * 64;            // shorts per B buffer
    __shared__ short Asm[2 * ABUF];
    __shared__ short Bsm[2 * BBUF];
    const int tid = threadIdx.x;
    const int w = tid >> 6, lane = tid & 63;
    const int wm = w / WN, wn = w % WN;

    // GROUP_M=8 swizzled block mapping
    int gX = gridDim.x, gY = gridDim.y;
    int pid = blockIdx.y * gX + blockIdx.x;
    int width = 8 * gX;
    int group = pid / width;
    int first = group * 8;
    int gsz = min(gY - first, 8);
    int by = first + (pid % gsz);
    int bx = (pid % width) / gsz;
    const int m0 = by * BM, n0 = bx * 128;

    floatx4 acc[4][FN] = {};

    // staging: lane -> (row-in-8 = lane>>3, slot = lane&7), global chunk = slot^row
    const int ro = lane >> 3;
    const int sl = lane & 7;
    const int gch = sl ^ ro;
    const ushort* aptr[BM / 32];
    short* alds[BM / 32];
#pragma unroll
    for (int i = 0; i < BM / 32; i++) {
        int r = w * AROWS + i * 8 + ro;
        int gr = min(m0 + r, M - 1);
        aptr[i] = A + (size_t)gr * K + gch * 8;
        alds[i] = Asm + (w * AROWS + i * 8) * 64;
    }
    const ushort* bptr[4];
    short* blds[4];
#pragma unroll
    for (int i = 0; i < 4; i++) {
        int r = w * 32 + i * 8 + ro;
        int gr = min(n0 + r, N - 1);
        bptr[i] = Wt + (size_t)gr * K + gch * 8;
        blds[i] = Bsm + (w * 32 + i * 8) * 64;
    }

    const int fr = lane & 15, quad = lane >> 4;

    const int nsteps = K >> 6;  // K-tiles of 64
    // prologue: stage tile 0 into buffer 0
#pragma unroll
    for (int i = 0; i < BM / 32; i++) async_copy16(aptr[i], alds[i]);
#pragma unroll
    for (int i = 0; i < 4; i++) async_copy16(bptr[i], blds[i]);

    int cur = 0;
    for (int t = 0; t < nsteps; ++t) {
        if (t + 1 < nsteps) {
            // issue next tile's loads into the other buffer (in flight across barrier)
            const int nxt = cur ^ 1;
            const int kk = (t + 1) << 6;
#pragma unroll
            for (int i = 0; i < BM / 32; i++) async_copy16(aptr[i] + kk, alds[i] + nxt * ABUF);
#pragma unroll
            for (int i = 0; i < 4; i++) async_copy16(bptr[i] + kk, blds[i] + nxt * BBUF);
            // wait only for the current tile's loads (NL newest stay outstanding)
            if constexpr (BM == 128) asm volatile("s_waitcnt vmcnt(8)" ::: "memory");
            else                     asm volatile("s_waitcnt vmcnt(6)" ::: "memory");
        } else {
            asm volatile("s_waitcnt vmcnt(0)" ::: "memory");
        }
        asm volatile("s_barrier" ::: "memory");

        const short* As = Asm + cur * ABUF;
        const short* Bs = Bsm + cur * BBUF;
#pragma unroll
        for (int ks = 0; ks < 2; ks++) {
            int soff = (((ks * 4 + quad) ^ (fr & 7)) * 8);
            short8 af[4], bf[FN];
#pragma unroll
            for (int mt = 0; mt < 4; mt++)
                af[mt] = *(const short8*)&As[(wm * 64 + mt * 16 + fr) * 64 + soff];
#pragma unroll
            for (int nt = 0; nt < FN; nt++)
                bf[nt] = *(const short8*)&Bs[(wn * (16 * FN) + nt * 16 + fr) * 64 + soff];
#pragma unroll
            for (int mt = 0; mt < 4; mt++)
#pragma unroll
                for (int nt = 0; nt < FN; nt++)
                    acc[mt][nt] = __builtin_amdgcn_mfma_f32_16x16x32_bf16(af[mt], bf[nt], acc[mt][nt], 0, 0, 0);
        }
        asm volatile("s_barrier" ::: "memory");
        cur ^= 1;
    }

#pragma unroll
    for (int nt = 0; nt < FN; nt++) {
        int col = n0 + wn * (16 * FN) + nt * 16 + fr;
        if (col >= N) continue;
        float bv = bias[col];
#pragma unroll
        for (int mt = 0; mt < 4; mt++) {
            int rbase = m0 + wm * 64 + mt * 16 + quad * 4;
#pragma unroll
            for (int r = 0; r < 4; r++) {
                int row = rbase + r;
                if (row >= M) continue;
                float v = acc[mt][nt][r] + bv;
                if (GELU) v = 0.5f * v * (1.0f + erff(v * 0.70710678118654752f));
                if (RES) v += res[(size_t)row * N + col];
                if (WF32) Cf[(size_t)row * N + col] = v;
                if (WBF16) Cb[(size_t)row * N + col] = f2bf(v);
            }
        }
    }
}

// ---------------------------------------------------------------------------
// MFMA attention (round-3 version, unchanged).
// ---------------------------------------------------------------------------
__global__ __launch_bounds__(256, 2) void attn_kernel(const ushort* __restrict__ qkvb,
                                                      const float* __restrict__ mask,
                                                      ushort* __restrict__ o) {
    const int h = blockIdx.x, b = blockIdx.y;
    const int tid = threadIdx.x;
    __shared__ ushort Vfrag[7 * 4 * 64 * 8];
    __shared__ ushort Pfrag[4 * 7 * 64 * 8];

    {
        uint4 z = {0, 0, 0, 0};
        uint4* v4 = (uint4*)Vfrag;
        uint4* p4 = (uint4*)Pfrag;
        for (int i = tid; i < 1792; i += 256) { v4[i] = z; p4[i] = z; }
    }
    __syncthreads();

    for (int pass = 0; pass < 25; pass++) {
        int j = pass * 8 + (tid >> 5);
        if (j <= 196) {
            int d0 = (tid & 31) * 2;
            unsigned int val = *(const unsigned int*)(qkvb + ((size_t)(b * N_TOK + j) * 3 + 2) * DIM + h * HD + d0);
            int kt = j >> 5, dt = d0 >> 4;
            int lane = ((j & 31) >> 3) * 16 + (d0 & 15);
            int jj = j & 7;
            int base = (kt * 4 + dt) * 512 + lane * 8 + jj;
            Vfrag[base] = (ushort)(val & 0xffffu);
            Vfrag[base + 8] = (ushort)(val >> 16);
        }
    }
    __syncthreads();

    const int w = tid >> 6, l = tid & 63;
    const int q = l >> 4, fr = l & 15;
    ushort* Pw = Pfrag + w * 3584;
    const float scale = 0.125f;

    for (int qt = w; qt < 13; qt += 4) {
        int qrow = min(qt * 16 + fr, 196);
        const ushort* qptr = qkvb + ((size_t)(b * N_TOK + qrow) * 3 + 0) * DIM + h * HD + q * 8;
        short8 aq0 = *(const short8*)qptr;
        short8 aq1 = *(const short8*)(qptr + 32);

        floatx4 sacc[13];
#pragma unroll
        for (int nt = 0; nt < 13; nt++) {
            int krow = min(nt * 16 + fr, 196);
            const ushort* kptr = qkvb + ((size_t)(b * N_TOK + krow) * 3 + 1) * DIM + h * HD + q * 8;
            short8 kb0 = *(const short8*)kptr;
            short8 kb1 = *(const short8*)(kptr + 32);
            floatx4 acc = {};
            acc = __builtin_amdgcn_mfma_f32_16x16x32_bf16(aq0, kb0, acc, 0, 0, 0);
            acc = __builtin_amdgcn_mfma_f32_16x16x32_bf16(aq1, kb1, acc, 0, 0, 0);
            sacc[nt] = acc;
        }

        float mx[4] = {-1e30f, -1e30f, -1e30f, -1e30f};
#pragma unroll
        for (int nt = 0; nt < 13; nt++) {
            int jcol = nt * 16 + fr;
#pragma unroll
            for (int r = 0; r < 4; r++) {
                int irow = min(qt * 16 + q * 4 + r, 196);
                float s;
                if (jcol <= 196) s = sacc[nt][r] * scale * mask[irow * N_TOK + jcol];
                else s = -1e30f;
                sacc[nt][r] = s;
                mx[r] = fmaxf(mx[r], s);
            }
        }
#pragma unroll
        for (int r = 0; r < 4; r++) {
            mx[r] = fmaxf(mx[r], __shfl_xor(mx[r], 1));
            mx[r] = fmaxf(mx[r], __shfl_xor(mx[r], 2));
            mx[r] = fmaxf(mx[r], __shfl_xor(mx[r], 4));
            mx[r] = fmaxf(mx[r], __shfl_xor(mx[r], 8));
        }

        float sum[4] = {0, 0, 0, 0};
#pragma unroll
        for (int nt = 0; nt < 13; nt++) {
            int kt = nt >> 1;
            int lpbase = ((nt & 1) * 2 + ((l & 8) >> 3)) * 16;
#pragma unroll
            for (int r = 0; r < 4; r++) {
                float e = __expf(sacc[nt][r] - mx[r]);
                sum[r] += e;
                int lp = (q * 4 + r) + lpbase;
                Pw[kt * 512 + lp * 8 + (l & 7)] = f2bf(e);
            }
        }
#pragma unroll
        for (int r = 0; r < 4; r++) {
            sum[r] += __shfl_xor(sum[r], 1);
            sum[r] += __shfl_xor(sum[r], 2);
            sum[r] += __shfl_xor(sum[r], 4);
            sum[r] += __shfl_xor(sum[r], 8);
        }

        floatx4 oacc[4] = {};
#pragma unroll
        for (int kt = 0; kt < 7; kt++) {
            short8 pa = *(const short8*)&Pw[kt * 512 + l * 8];
#pragma unroll
            for (int dt = 0; dt < 4; dt++) {
                short8 vb = *(const short8*)&Vfrag[(kt * 4 + dt) * 512 + l * 8];
                oacc[dt] = __builtin_amdgcn_mfma_f32_16x16x32_bf16(pa, vb, oacc[dt], 0, 0, 0);
            }
        }

        float inv[4];
#pragma unroll
        for (int r = 0; r < 4; r++) inv[r] = 1.0f / sum[r];
#pragma unroll
        for (int dt = 0; dt < 4; dt++) {
#pragma unroll
            for (int r = 0; r < 4; r++) {
                int irow = qt * 16 + q * 4 + r;
                if (irow <= 196)
                    o[((size_t)(b * N_TOK + irow)) * DIM + h * HD + dt * 16 + fr] = f2bf(oacc[dt][r] * inv[r]);
            }
        }
    }
}

// ---------------------------------------------------------------------------
extern "C" void kernel_launch(void* const* d_in, const int* in_sizes, int n_in,
                              void* d_out, int out_size, void* d_ws, size_t ws_size,
                              hipStream_t stream) {
    const float* x       = (const float*)d_in[0];
    const float* cp_mask = (const float*)d_in[1];
    const float* patch_w = (const float*)d_in[2];
    const float* patch_b = (const float*)d_in[3];
    const float* cls_tok = (const float*)d_in[4];
    const float* pos_emb = (const float*)d_in[5];
    const float* ln1_g   = (const float*)d_in[6];
    const float* ln1_b   = (const float*)d_in[7];
    const float* qkv_w   = (const float*)d_in[8];
    const float* qkv_b   = (const float*)d_in[9];
    const float* proj_w  = (const float*)d_in[10];
    const float* proj_b  = (const float*)d_in[11];
    const float* ln2_g   = (const float*)d_in[12];
    const float* ln2_b   = (const float*)d_in[13];
    const float* fc1_w   = (const float*)d_in[14];
    const float* fc1_b   = (const float*)d_in[15];
    const float* fc2_w   = (const float*)d_in[16];
    const float* fc2_b   = (const float*)d_in[17];
    const float* normf_g = (const float*)d_in[18];
    const float* normf_b = (const float*)d_in[19];
    const float* head_w  = (const float*)d_in[20];
    const float* head_b  = (const float*)d_in[21];
    float* out = (float*)d_out;

    const int M = BATCH * N_TOK;  // 6304
    char* p = (char*)d_ws;
    auto alloc = [&](size_t bytes) { char* r = p; p += (bytes + 255) & ~(size_t)255; return r; };
    float*  t         = (float*)alloc((size_t)M * DIM * 4);
    float*  patchout  = (float*)alloc((size_t)BATCH * NPATCH * DIM * 4);
    ushort* h_bf      = (ushort*)alloc((size_t)M * DIM * 2);
    ushort* qkv_bf    = (ushort*)alloc((size_t)M * 3 * DIM * 2);
    ushort* o_bf      = (ushort*)alloc((size_t)M * DIM * 2);
    ushort* hidden_bf = (ushort*)alloc((size_t)M * MLP_DIM * 2);
    ushort* pooled_bf = (ushort*)alloc((size_t)BATCH * DIM * 2);
    ushort* wq_t      = (ushort*)alloc((size_t)3 * DIM * DIM * 2);
    ushort* wp_t      = (ushort*)alloc((size_t)DIM * DIM * 2);
    ushort* w1_t      = (ushort*)alloc((size_t)MLP_DIM * DIM * 2);
    ushort* w2_t      = (ushort*)alloc((size_t)DIM * MLP_DIM * 2);
    ushort* wpt       = (ushort*)alloc((size_t)DIM * DIM * 2);
    ushort* wht       = (ushort*)alloc((size_t)NCLS * DIM * 2);

    const dim3 tb(32, 8);

    transpose_bf16_kernel<<<dim3(24, 24), tb, 0, stream>>>(patch_w, wpt, DIM, DIM);
    transpose_bf16_kernel<<<dim3(32, 24), tb, 0, stream>>>(head_w, wht, DIM, NCLS);
    {
        int total = BATCH * NPATCH * DIM;
        im2col_kernel<<<(total + 255) / 256, 256, 0, stream>>>(x, h_bf);
        gemm_bf16_mfma<64, 0, 0, 1, 0><<<dim3(6, 98), 256, 0, stream>>>(
            h_bf, wpt, patch_b, nullptr, patchout, nullptr, BATCH * NPATCH, DIM, DIM);
        int total2 = M * DIM;
        assemble_kernel<<<(total2 + 255) / 256, 256, 0, stream>>>(patchout, cls_tok, pos_emb, t);
    }

    for (int l = 0; l < DEPTH; l++) {
        transpose4_kernel<<<6912, tb, 0, stream>>>(
            qkv_w + (size_t)l * DIM * 3 * DIM, proj_w + (size_t)l * DIM * DIM,
            fc1_w + (size_t)l * DIM * MLP_DIM, fc2_w + (size_t)l * MLP_DIM * DIM,
            wq_t, wp_t, w1_t, w2_t);

        lnw_kernel<<<M / 4, 256, 0, stream>>>(t, ln1_g + l * DIM, ln1_b + l * DIM, h_bf, M, DIM, DIM);

        gemm_bf16_mfma<128, 0, 0, 0, 1><<<dim3(18, 50), 256, 0, stream>>>(
            h_bf, wq_t, qkv_b + (size_t)l * 3 * DIM, nullptr, nullptr, qkv_bf, M, 3 * DIM, DIM);

        attn_kernel<<<dim3(HEADS, BATCH), 256, 0, stream>>>(qkv_bf, cp_mask, o_bf);

        gemm_bf16_mfma<64, 0, 1, 1, 0><<<dim3(6, 99), 256, 0, stream>>>(
            o_bf, wp_t, proj_b + (size_t)l * DIM, t, t, nullptr, M, DIM, DIM);

        lnw_kernel<<<M / 4, 256, 0, stream>>>(t, ln2_g + l * DIM, ln2_b + l * DIM, h_bf, M, DIM, DIM);

        gemm_bf16_mfma<128, 1, 0, 0, 1><<<dim3(24, 50), 256, 0, stream>>>(
            h_bf, w1_t, fc1_b + (size_t)l * MLP_DIM, nullptr, nullptr, hidden_bf, M, MLP_DIM, DIM);

        gemm_bf16_mfma<64, 0, 1, 1, 0><<<dim3(6, 99), 256, 0, stream>>>(
            hidden_bf, w2_t, fc2_b + (size_t)l * DIM, t, t, nullptr, M, DIM, MLP_DIM);
    }

    lnw_kernel<<<8, 256, 0, stream>>>(t, normf_g, normf_b, pooled_bf, BATCH, N_TOK * DIM, DIM);
    gemm_bf16_mfma<64, 0, 0, 1, 0><<<dim3(8, 1), 256, 0, stream>>>(
        pooled_bf, wht, head_b, nullptr, out, nullptr, BATCH, NCLS, DIM);
}

// Round 2
// 3203.957 us; speedup vs baseline: 1.0775x; 1.0775x over previous
//
#include <hip/hip_runtime.h>
#include <math.h>

#define BATCH 32
#define DEPTH 12
#define DIM 768
#define HEADS 12
#define MLP_DIM 3072
#define PATCH 16
#define GRIDSZ 14
#define NCLS 1000
#define N_TOK 197
#define HD 64
#define NPATCH 196

typedef __attribute__((ext_vector_type(8))) short short8;
typedef __attribute__((ext_vector_type(4))) float floatx4;
typedef unsigned short ushort;

__device__ inline float us2f(ushort u) {
    union { unsigned int i; float f; } c; c.i = ((unsigned int)u) << 16; return c.f;
}
__device__ inline ushort f2bf(float f) {
    unsigned int x = __float_as_uint(f);
    unsigned int r = (x + 0x7fffu + ((x >> 16) & 1u)) >> 16;
    return (ushort)r;
}

// Fast exact-GELU: 0.5x(1+erf(x/sqrt2)) with Abramowitz-Stegun 7.1.26 erf
// (|err| <= 1.5e-7, far below bf16 ulp). ~15 VALU vs ~30 for libm erff.
__device__ inline float gelu_fast(float v) {
    float y = fabsf(v) * 0.70710678118654752f;
    float t = __builtin_amdgcn_rcpf(__builtin_fmaf(0.3275911f, y, 1.0f));
    float p = t * (0.254829592f + t * (-0.284496736f + t * (1.421413741f + t * (-1.453152027f + t * 1.061405429f))));
    float e = p * __expf(-y * y);
    float erfv = 1.0f - e;
    float s = (v >= 0.0f) ? erfv : -erfv;
    return 0.5f * v * (1.0f + s);
}

#define GAS __attribute__((address_space(1)))
#define LAS __attribute__((address_space(3)))
__device__ inline void async_copy16(const void* g, void* l) {
    __builtin_amdgcn_global_load_lds((const GAS void*)g, (LAS void*)l, 16, 0, 0);
}

// ---------------------------------------------------------------------------
__global__ __launch_bounds__(256) void im2col_kernel(const float* __restrict__ x,
                                                     ushort* __restrict__ patches) {
    int idx = blockIdx.x * 256 + threadIdx.x;
    const int total = BATCH * NPATCH * DIM;
    if (idx >= total) return;
    int e = idx % DIM;
    int n = (idx / DIM) % NPATCH;
    int b = idx / (DIM * NPATCH);
    int c = e / (PATCH * PATCH);
    int r = e % (PATCH * PATCH);
    int py = r / PATCH, px = r % PATCH;
    int gy = n / GRIDSZ, gx = n % GRIDSZ;
    size_t xi = (((size_t)(b * 3 + c) * 224 + gy * PATCH + py)) * 224 + gx * PATCH + px;
    patches[idx] = f2bf(x[xi]);
}

// ---------------------------------------------------------------------------
__global__ __launch_bounds__(256) void assemble_kernel(const float* __restrict__ patchout,
                                                       const float* __restrict__ cls,
                                                       const float* __restrict__ pos,
                                                       float* __restrict__ t) {
    int idx = blockIdx.x * 256 + threadIdx.x;
    const int total = BATCH * N_TOK * DIM;
    if (idx >= total) return;
    int d = idx % DIM;
    int n = (idx / DIM) % N_TOK;
    int b = idx / (DIM * N_TOK);
    float v = (n == 0) ? cls[d] : patchout[((size_t)b * NPATCH + (n - 1)) * DIM + d];
    t[idx] = v + pos[n * DIM + d];
}

// ---------------------------------------------------------------------------
// LayerNorm, wave-per-row: block = 4 waves = 4 rows. 768 = 64 lanes * 12.
// ---------------------------------------------------------------------------
__global__ __launch_bounds__(256) void lnw_kernel(const float* __restrict__ x,
                                                  const float* __restrict__ g,
                                                  const float* __restrict__ bta,
                                                  ushort* __restrict__ out,
                                                  int rows, int in_stride, int out_stride) {
    int w = threadIdx.x >> 6, l = threadIdx.x & 63;
    int row = blockIdx.x * 4 + w;
    if (row >= rows) return;
    const float* xr = x + (size_t)row * in_stride;
    float4 v[3];
    float s = 0.0f, s2 = 0.0f;
#pragma unroll
    for (int c = 0; c < 3; c++) {
        v[c] = *(const float4*)(xr + c * 256 + l * 4);
        s  += v[c].x + v[c].y + v[c].z + v[c].w;
        s2 += v[c].x * v[c].x + v[c].y * v[c].y + v[c].z * v[c].z + v[c].w * v[c].w;
    }
#pragma unroll
    for (int off = 32; off; off >>= 1) { s += __shfl_xor(s, off); s2 += __shfl_xor(s2, off); }
    float mean = s * (1.0f / DIM);
    float inv = rsqrtf(s2 * (1.0f / DIM) - mean * mean + 1e-6f);
    ushort* orow = out + (size_t)row * out_stride;
#pragma unroll
    for (int c = 0; c < 3; c++) {
        float4 gg = *(const float4*)(g + c * 256 + l * 4);
        float4 bb = *(const float4*)(bta + c * 256 + l * 4);
        ushort4 o4;
        o4.x = f2bf((v[c].x - mean) * inv * gg.x + bb.x);
        o4.y = f2bf((v[c].y - mean) * inv * gg.y + bb.y);
        o4.z = f2bf((v[c].z - mean) * inv * gg.z + bb.z);
        o4.w = f2bf((v[c].w - mean) * inv * gg.w + bb.w);
        *(ushort4*)(orow + c * 256 + l * 4) = o4;
    }
}

// ---------------------------------------------------------------------------
// Bounded transpose (pre-loop: patch_w, head_w). in KxN -> out NxK bf16.
// ---------------------------------------------------------------------------
__global__ __launch_bounds__(256) void transpose_bf16_kernel(const float* __restrict__ in,
                                                             ushort* __restrict__ out,
                                                             int K, int N) {
    __shared__ float tile[32][33];
    int n0 = blockIdx.x * 32, k0 = blockIdx.y * 32;
    int tx = threadIdx.x;
    int ty = threadIdx.y;
    for (int r = ty; r < 32; r += 8) {
        int k = k0 + r, n = n0 + tx;
        tile[r][tx] = (k < K && n < N) ? in[(size_t)k * N + n] : 0.0f;
    }
    __syncthreads();
    for (int r = ty; r < 32; r += 8) {
        int n = n0 + r, k = k0 + tx;
        if (n < N && k < K) out[(size_t)n * K + k] = f2bf(tile[tx][r]);
    }
}

// ---------------------------------------------------------------------------
// Batched per-layer transpose of the 4 weight mats (all dims %32==0).
// tiles: qkv 72x24=1728 | proj 24x24=576 | fc1 96x24=2304 | fc2 24x96=2304
// ---------------------------------------------------------------------------
__global__ __launch_bounds__(256) void transpose4_kernel(
    const float* __restrict__ w0, const float* __restrict__ w1,
    const float* __restrict__ w2, const float* __restrict__ w3,
    ushort* __restrict__ o0, ushort* __restrict__ o1,
    ushort* __restrict__ o2, ushort* __restrict__ o3) {
    __shared__ float tile[32][33];
    int bid = blockIdx.x;
    const float* in; ushort* out; int K, N, nx, tl;
    if (bid < 1728)      { in = w0; out = o0; K = 768;  N = 2304; nx = 72; tl = bid; }
    else if (bid < 2304) { in = w1; out = o1; K = 768;  N = 768;  nx = 24; tl = bid - 1728; }
    else if (bid < 4608) { in = w2; out = o2; K = 768;  N = 3072; nx = 96; tl = bid - 2304; }
    else                 { in = w3; out = o3; K = 3072; N = 768;  nx = 24; tl = bid - 4608; }
    int n0 = (tl % nx) * 32, k0 = (tl / nx) * 32;
    int tx = threadIdx.x, ty = threadIdx.y;
    for (int r = ty; r < 32; r += 8)
        tile[r][tx] = in[(size_t)(k0 + r) * N + n0 + tx];
    __syncthreads();
    for (int r = ty; r < 32; r += 8)
        out[(size_t)(n0 + r) * K + k0 + tx] = f2bf(tile[tx][r]);
}

// ---------------------------------------------------------------------------
// bf16 MFMA GEMM: BMx128x64 tiles (BM=128 or 64), 4 waves, 16x16x32 MFMA.
// XOR-swizzled LDS chunks (conflict-free ds_read_b128), GROUP_M=8 block
// swizzle for L2 locality. Wt is NxK (row n = col n of W).
//
// Round-5 structure, per-path (from the round-4 post-mortem):
//  * BM=128 (qkv/fc1, K=768): single-buffer + __syncthreads. These kernels
//    live on cross-block TLP (32KB LDS -> 5 blocks/CU, ~20 waves/CU);
//    round-4's 64KB dbuf cut residency to 2 blocks/CU and cost 15%.
//  * BM=64 (proj/fc2/patch/head): double-buffer + counted vmcnt(6) + raw
//    s_barrier. LDS 48KB keeps the same 3-blocks/CU residency (grids here
//    are <= 594 blocks, all co-resident either way), so the cross-barrier
//    load pipelining is free.
// ---------------------------------------------------------------------------
template <int BM, int GELU, int RES, int WF32, int WBF16>
__global__ __launch_bounds__(256) void gemm_bf16_mfma(
    const ushort* __restrict__ A, const ushort* __restrict__ Wt,
    const float* __restrict__ bias, const float* __restrict__ res,
    float* __restrict__ Cf, ushort* __restrict__ Cb,
    int M, int N, int K) {
    constexpr int WN = (BM == 128) ? 2 : 4;   // waves along N
    constexpr int FN = (BM == 128) ? 4 : 2;   // 16-col frags per wave
    constexpr int AROWS = BM / 4;             // A rows staged per wave
    constexpr int ABUF = BM * 64;             // shorts per A buffer
    constexpr int BBUF = 128 * 64;            // shorts per B buffer
    constexpr int DBUF = (BM == 64) ? 2 : 1;  // double-buffer only for BM=64
    __shared__ short Asm[DBUF * ABUF];
    __shared__ short Bsm[DBUF * BBUF];
    const int tid = threadIdx.x;
    const int w = tid >> 6, lane = tid & 63;
    const int wm = w / WN, wn = w % WN;

    // GROUP_M=8 swizzled block mapping
    int gX = gridDim.x, gY = gridDim.y;
    int pid = blockIdx.y * gX + blockIdx.x;
    int width = 8 * gX;
    int group = pid / width;
    int first = group * 8;
    int gsz = min(gY - first, 8);
    int by = first + (pid % gsz);
    int bx = (pid % width) / gsz;
    const int m0 = by * BM, n0 = bx * 128;

    floatx4 acc[4][FN] = {};

    // staging: lane -> (row-in-8 = lane>>3, slot = lane&7), global chunk = slot^row
    const int ro = lane >> 3;
    const int sl = lane & 7;
    const int gch = sl ^ ro;
    const ushort* aptr[BM / 32];
    short* alds[BM / 32];
#pragma unroll
    for (int i = 0; i < BM / 32; i++) {
        int r = w * AROWS + i * 8 + ro;
        int gr = min(m0 + r, M - 1);
        aptr[i] = A + (size_t)gr * K + gch * 8;
        alds[i] = Asm + (w * AROWS + i * 8) * 64;
    }
    const ushort* bptr[4];
    short* blds[4];
#pragma unroll
    for (int i = 0; i < 4; i++) {
        int r = w * 32 + i * 8 + ro;
        int gr = min(n0 + r, N - 1);
        bptr[i] = Wt + (size_t)gr * K + gch * 8;
        blds[i] = Bsm + (w * 32 + i * 8) * 64;
    }

    const int fr = lane & 15, quad = lane >> 4;

    auto compute_tile = [&](const short* As, const short* Bs) {
#pragma unroll
        for (int ks = 0; ks < 2; ks++) {
            int soff = (((ks * 4 + quad) ^ (fr & 7)) * 8);
            short8 af[4], bfv[FN];
#pragma unroll
            for (int mt = 0; mt < 4; mt++)
                af[mt] = *(const short8*)&As[(wm * 64 + mt * 16 + fr) * 64 + soff];
#pragma unroll
            for (int nt = 0; nt < FN; nt++)
                bfv[nt] = *(const short8*)&Bs[(wn * (16 * FN) + nt * 16 + fr) * 64 + soff];
#pragma unroll
            for (int mt = 0; mt < 4; mt++)
#pragma unroll
                for (int nt = 0; nt < FN; nt++)
                    acc[mt][nt] = __builtin_amdgcn_mfma_f32_16x16x32_bf16(af[mt], bfv[nt], acc[mt][nt], 0, 0, 0);
        }
    };

    if constexpr (BM == 64) {
        const int nsteps = K >> 6;
        // prologue: stage tile 0 into buffer 0
#pragma unroll
        for (int i = 0; i < BM / 32; i++) async_copy16(aptr[i], alds[i]);
#pragma unroll
        for (int i = 0; i < 4; i++) async_copy16(bptr[i], blds[i]);
        int cur = 0;
        for (int t = 0; t < nsteps; ++t) {
            if (t + 1 < nsteps) {
                const int nxt = cur ^ 1;
                const int kk = (t + 1) << 6;
#pragma unroll
                for (int i = 0; i < BM / 32; i++) async_copy16(aptr[i] + kk, alds[i] + nxt * ABUF);
#pragma unroll
                for (int i = 0; i < 4; i++) async_copy16(bptr[i] + kk, blds[i] + nxt * BBUF);
                // wait only for the current tile's 6 loads; next tile's stay in flight
                asm volatile("s_waitcnt vmcnt(6)" ::: "memory");
            } else {
                asm volatile("s_waitcnt vmcnt(0)" ::: "memory");
            }
            asm volatile("s_barrier" ::: "memory");
            compute_tile(Asm + cur * ABUF, Bsm + cur * BBUF);
            asm volatile("s_barrier" ::: "memory");
            cur ^= 1;
        }
    } else {
        for (int k0 = 0; k0 < K; k0 += 64) {
#pragma unroll
            for (int i = 0; i < BM / 32; i++) async_copy16(aptr[i] + k0, alds[i]);
#pragma unroll
            for (int i = 0; i < 4; i++) async_copy16(bptr[i] + k0, blds[i]);
            __syncthreads();
            compute_tile(Asm, Bsm);
            __syncthreads();
        }
    }

#pragma unroll
    for (int nt = 0; nt < FN; nt++) {
        int col = n0 + wn * (16 * FN) + nt * 16 + fr;
        if (col >= N) continue;
        float bv = bias[col];
#pragma unroll
        for (int mt = 0; mt < 4; mt++) {
            int rbase = m0 + wm * 64 + mt * 16 + quad * 4;
#pragma unroll
            for (int r = 0; r < 4; r++) {
                int row = rbase + r;
                if (row >= M) continue;
                float v = acc[mt][nt][r] + bv;
                if (GELU) v = gelu_fast(v);
                if (RES) v += res[(size_t)row * N + col];
                if (WF32) Cf[(size_t)row * N + col] = v;
                if (WBF16) Cb[(size_t)row * N + col] = f2bf(v);
            }
        }
    }
}

// ---------------------------------------------------------------------------
// MFMA attention (round-3 version, unchanged).
// ---------------------------------------------------------------------------
__global__ __launch_bounds__(256, 2) void attn_kernel(const ushort* __restrict__ qkvb,
                                                      const float* __restrict__ mask,
                                                      ushort* __restrict__ o) {
    const int h = blockIdx.x, b = blockIdx.y;
    const int tid = threadIdx.x;
    __shared__ ushort Vfrag[7 * 4 * 64 * 8];
    __shared__ ushort Pfrag[4 * 7 * 64 * 8];

    {
        uint4 z = {0, 0, 0, 0};
        uint4* v4 = (uint4*)Vfrag;
        uint4* p4 = (uint4*)Pfrag;
        for (int i = tid; i < 1792; i += 256) { v4[i] = z; p4[i] = z; }
    }
    __syncthreads();

    for (int pass = 0; pass < 25; pass++) {
        int j = pass * 8 + (tid >> 5);
        if (j <= 196) {
            int d0 = (tid & 31) * 2;
            unsigned int val = *(const unsigned int*)(qkvb + ((size_t)(b * N_TOK + j) * 3 + 2) * DIM + h * HD + d0);
            int kt = j >> 5, dt = d0 >> 4;
            int lane = ((j & 31) >> 3) * 16 + (d0 & 15);
            int jj = j & 7;
            int base = (kt * 4 + dt) * 512 + lane * 8 + jj;
            Vfrag[base] = (ushort)(val & 0xffffu);
            Vfrag[base + 8] = (ushort)(val >> 16);
        }
    }
    __syncthreads();

    const int w = tid >> 6, l = tid & 63;
    const int q = l >> 4, fr = l & 15;
    ushort* Pw = Pfrag + w * 3584;
    const float scale = 0.125f;

    for (int qt = w; qt < 13; qt += 4) {
        int qrow = min(qt * 16 + fr, 196);
        const ushort* qptr = qkvb + ((size_t)(b * N_TOK + qrow) * 3 + 0) * DIM + h * HD + q * 8;
        short8 aq0 = *(const short8*)qptr;
        short8 aq1 = *(const short8*)(qptr + 32);

        floatx4 sacc[13];
#pragma unroll
        for (int nt = 0; nt < 13; nt++) {
            int krow = min(nt * 16 + fr, 196);
            const ushort* kptr = qkvb + ((size_t)(b * N_TOK + krow) * 3 + 1) * DIM + h * HD + q * 8;
            short8 kb0 = *(const short8*)kptr;
            short8 kb1 = *(const short8*)(kptr + 32);
            floatx4 acc = {};
            acc = __builtin_amdgcn_mfma_f32_16x16x32_bf16(aq0, kb0, acc, 0, 0, 0);
            acc = __builtin_amdgcn_mfma_f32_16x16x32_bf16(aq1, kb1, acc, 0, 0, 0);
            sacc[nt] = acc;
        }

        float mx[4] = {-1e30f, -1e30f, -1e30f, -1e30f};
#pragma unroll
        for (int nt = 0; nt < 13; nt++) {
            int jcol = nt * 16 + fr;
#pragma unroll
            for (int r = 0; r < 4; r++) {
                int irow = min(qt * 16 + q * 4 + r, 196);
                float s;
                if (jcol <= 196) s = sacc[nt][r] * scale * mask[irow * N_TOK + jcol];
                else s = -1e30f;
                sacc[nt][r] = s;
                mx[r] = fmaxf(mx[r], s);
            }
        }
#pragma unroll
        for (int r = 0; r < 4; r++) {
            mx[r] = fmaxf(mx[r], __shfl_xor(mx[r], 1));
            mx[r] = fmaxf(mx[r], __shfl_xor(mx[r], 2));
            mx[r] = fmaxf(mx[r], __shfl_xor(mx[r], 4));
            mx[r] = fmaxf(mx[r], __shfl_xor(mx[r], 8));
        }

        float sum[4] = {0, 0, 0, 0};
#pragma unroll
        for (int nt = 0; nt < 13; nt++) {
            int kt = nt >> 1;
            int lpbase = ((nt & 1) * 2 + ((l & 8) >> 3)) * 16;
#pragma unroll
            for (int r = 0; r < 4; r++) {
                float e = __expf(sacc[nt][r] - mx[r]);
                sum[r] += e;
                int lp = (q * 4 + r) + lpbase;
                Pw[kt * 512 + lp * 8 + (l & 7)] = f2bf(e);
            }
        }
#pragma unroll
        for (int r = 0; r < 4; r++) {
            sum[r] += __shfl_xor(sum[r], 1);
            sum[r] += __shfl_xor(sum[r], 2);
            sum[r] += __shfl_xor(sum[r], 4);
            sum[r] += __shfl_xor(sum[r], 8);
        }

        floatx4 oacc[4] = {};
#pragma unroll
        for (int kt = 0; kt < 7; kt++) {
            short8 pa = *(const short8*)&Pw[kt * 512 + l * 8];
#pragma unroll
            for (int dt = 0; dt < 4; dt++) {
                short8 vb = *(const short8*)&Vfrag[(kt * 4 + dt) * 512 + l * 8];
                oacc[dt] = __builtin_amdgcn_mfma_f32_16x16x32_bf16(pa, vb, oacc[dt], 0, 0, 0);
            }
        }

        float inv[4];
#pragma unroll
        for (int r = 0; r < 4; r++) inv[r] = 1.0f / sum[r];
#pragma unroll
        for (int dt = 0; dt < 4; dt++) {
#pragma unroll
            for (int r = 0; r < 4; r++) {
                int irow = qt * 16 + q * 4 + r;
                if (irow <= 196)
                    o[((size_t)(b * N_TOK + irow)) * DIM + h * HD + dt * 16 + fr] = f2bf(oacc[dt][r] * inv[r]);
            }
        }
    }
}

// ---------------------------------------------------------------------------
extern "C" void kernel_launch(void* const* d_in, const int* in_sizes, int n_in,
                              void* d_out, int out_size, void* d_ws, size_t ws_size,
                              hipStream_t stream) {
    const float* x       = (const float*)d_in[0];
    const float* cp_mask = (const float*)d_in[1];
    const float* patch_w = (const float*)d_in[2];
    const float* patch_b = (const float*)d_in[3];
    const float* cls_tok = (const float*)d_in[4];
    const float* pos_emb = (const float*)d_in[5];
    const float* ln1_g   = (const float*)d_in[6];
    const float* ln1_b   = (const float*)d_in[7];
    const float* qkv_w   = (const float*)d_in[8];
    const float* qkv_b   = (const float*)d_in[9];
    const float* proj_w  = (const float*)d_in[10];
    const float* proj_b  = (const float*)d_in[11];
    const float* ln2_g   = (const float*)d_in[12];
    const float* ln2_b   = (const float*)d_in[13];
    const float* fc1_w   = (const float*)d_in[14];
    const float* fc1_b   = (const float*)d_in[15];
    const float* fc2_w   = (const float*)d_in[16];
    const float* fc2_b   = (const float*)d_in[17];
    const float* normf_g = (const float*)d_in[18];
    const float* normf_b = (const float*)d_in[19];
    const float* head_w  = (const float*)d_in[20];
    const float* head_b  = (const float*)d_in[21];
    float* out = (float*)d_out;

    const int M = BATCH * N_TOK;  // 6304
    char* p = (char*)d_ws;
    auto alloc = [&](size_t bytes) { char* r = p; p += (bytes + 255) & ~(size_t)255; return r; };
    float*  t         = (float*)alloc((size_t)M * DIM * 4);
    float*  patchout  = (float*)alloc((size_t)BATCH * NPATCH * DIM * 4);
    ushort* h_bf      = (ushort*)alloc((size_t)M * DIM * 2);
    ushort* qkv_bf    = (ushort*)alloc((size_t)M * 3 * DIM * 2);
    ushort* o_bf      = (ushort*)alloc((size_t)M * DIM * 2);
    ushort* hidden_bf = (ushort*)alloc((size_t)M * MLP_DIM * 2);
    ushort* pooled_bf = (ushort*)alloc((size_t)BATCH * DIM * 2);
    ushort* wq_t      = (ushort*)alloc((size_t)3 * DIM * DIM * 2);
    ushort* wp_t      = (ushort*)alloc((size_t)DIM * DIM * 2);
    ushort* w1_t      = (ushort*)alloc((size_t)MLP_DIM * DIM * 2);
    ushort* w2_t      = (ushort*)alloc((size_t)DIM * MLP_DIM * 2);
    ushort* wpt       = (ushort*)alloc((size_t)DIM * DIM * 2);
    ushort* wht       = (ushort*)alloc((size_t)NCLS * DIM * 2);

    const dim3 tb(32, 8);

    transpose_bf16_kernel<<<dim3(24, 24), tb, 0, stream>>>(patch_w, wpt, DIM, DIM);
    transpose_bf16_kernel<<<dim3(32, 24), tb, 0, stream>>>(head_w, wht, DIM, NCLS);
    {
        int total = BATCH * NPATCH * DIM;
        im2col_kernel<<<(total + 255) / 256, 256, 0, stream>>>(x, h_bf);
        gemm_bf16_mfma<64, 0, 0, 1, 0><<<dim3(6, 98), 256, 0, stream>>>(
            h_bf, wpt, patch_b, nullptr, patchout, nullptr, BATCH * NPATCH, DIM, DIM);
        int total2 = M * DIM;
        assemble_kernel<<<(total2 + 255) / 256, 256, 0, stream>>>(patchout, cls_tok, pos_emb, t);
    }

    for (int l = 0; l < DEPTH; l++) {
        transpose4_kernel<<<6912, tb, 0, stream>>>(
            qkv_w + (size_t)l * DIM * 3 * DIM, proj_w + (size_t)l * DIM * DIM,
            fc1_w + (size_t)l * DIM * MLP_DIM, fc2_w + (size_t)l * MLP_DIM * DIM,
            wq_t, wp_t, w1_t, w2_t);

        lnw_kernel<<<M / 4, 256, 0, stream>>>(t, ln1_g + l * DIM, ln1_b + l * DIM, h_bf, M, DIM, DIM);

        gemm_bf16_mfma<128, 0, 0, 0, 1><<<dim3(18, 50), 256, 0, stream>>>(
            h_bf, wq_t, qkv_b + (size_t)l * 3 * DIM, nullptr, nullptr, qkv_bf, M, 3 * DIM, DIM);

        attn_kernel<<<dim3(HEADS, BATCH), 256, 0, stream>>>(qkv_bf, cp_mask, o_bf);

        gemm_bf16_mfma<64, 0, 1, 1, 0><<<dim3(6, 99), 256, 0, stream>>>(
            o_bf, wp_t, proj_b + (size_t)l * DIM, t, t, nullptr, M, DIM, DIM);

        lnw_kernel<<<M / 4, 256, 0, stream>>>(t, ln2_g + l * DIM, ln2_b + l * DIM, h_bf, M, DIM, DIM);

        gemm_bf16_mfma<128, 1, 0, 0, 1><<<dim3(24, 50), 256, 0, stream>>>(
            h_bf, w1_t, fc1_b + (size_t)l * MLP_DIM, nullptr, nullptr, hidden_bf, M, MLP_DIM, DIM);

        gemm_bf16_mfma<64, 0, 1, 1, 0><<<dim3(6, 99), 256, 0, stream>>>(
            hidden_bf, w2_t, fc2_b + (size_t)l * DIM, t, t, nullptr, M, DIM, MLP_DIM);
    }

    lnw_kernel<<<8, 256, 0, stream>>>(t, normf_g, normf_b, pooled_bf, BATCH, N_TOK * DIM, DIM);
    gemm_bf16_mfma<64, 0, 0, 1, 0><<<dim3(8, 1), 256, 0, stream>>>(
        pooled_bf, wht, head_b, nullptr, out, nullptr, BATCH, NCLS, DIM);
}

// Round 3
// 2971.551 us; speedup vs baseline: 1.1618x; 1.0782x over previous
//
#include <hip/hip_runtime.h>
#include <math.h>

#define BATCH 32
#define DEPTH 12
#define DIM 768
#define HEADS 12
#define MLP_DIM 3072
#define PATCH 16
#define GRIDSZ 14
#define NCLS 1000
#define N_TOK 197
#define HD 64
#define NPATCH 196

typedef __attribute__((ext_vector_type(8))) short short8;
typedef __attribute__((ext_vector_type(4))) float floatx4;
typedef unsigned short ushort;

__device__ inline float us2f(ushort u) {
    union { unsigned int i; float f; } c; c.i = ((unsigned int)u) << 16; return c.f;
}
__device__ inline ushort f2bf(float f) {
    unsigned int x = __float_as_uint(f);
    unsigned int r = (x + 0x7fffu + ((x >> 16) & 1u)) >> 16;
    return (ushort)r;
}

// Fast exact-GELU: 0.5x(1+erf(x/sqrt2)) with Abramowitz-Stegun 7.1.26 erf
// (|err| <= 1.5e-7, far below bf16 ulp). ~15 VALU vs ~30 for libm erff.
__device__ inline float gelu_fast(float v) {
    float y = fabsf(v) * 0.70710678118654752f;
    float t = __builtin_amdgcn_rcpf(__builtin_fmaf(0.3275911f, y, 1.0f));
    float p = t * (0.254829592f + t * (-0.284496736f + t * (1.421413741f + t * (-1.453152027f + t * 1.061405429f))));
    float e = p * __expf(-y * y);
    float erfv = 1.0f - e;
    float s = (v >= 0.0f) ? erfv : -erfv;
    return 0.5f * v * (1.0f + s);
}

#define GAS __attribute__((address_space(1)))
#define LAS __attribute__((address_space(3)))
__device__ inline void async_copy16(const void* g, void* l) {
    __builtin_amdgcn_global_load_lds((const GAS void*)g, (LAS void*)l, 16, 0, 0);
}

// ---------------------------------------------------------------------------
__global__ __launch_bounds__(256) void im2col_kernel(const float* __restrict__ x,
                                                     ushort* __restrict__ patches) {
    int idx = blockIdx.x * 256 + threadIdx.x;
    const int total = BATCH * NPATCH * DIM;
    if (idx >= total) return;
    int e = idx % DIM;
    int n = (idx / DIM) % NPATCH;
    int b = idx / (DIM * NPATCH);
    int c = e / (PATCH * PATCH);
    int r = e % (PATCH * PATCH);
    int py = r / PATCH, px = r % PATCH;
    int gy = n / GRIDSZ, gx = n % GRIDSZ;
    size_t xi = (((size_t)(b * 3 + c) * 224 + gy * PATCH + py)) * 224 + gx * PATCH + px;
    patches[idx] = f2bf(x[xi]);
}

// ---------------------------------------------------------------------------
__global__ __launch_bounds__(256) void assemble_kernel(const float* __restrict__ patchout,
                                                       const float* __restrict__ cls,
                                                       const float* __restrict__ pos,
                                                       float* __restrict__ t) {
    int idx = blockIdx.x * 256 + threadIdx.x;
    const int total = BATCH * N_TOK * DIM;
    if (idx >= total) return;
    int d = idx % DIM;
    int n = (idx / DIM) % N_TOK;
    int b = idx / (DIM * N_TOK);
    float v = (n == 0) ? cls[d] : patchout[((size_t)b * NPATCH + (n - 1)) * DIM + d];
    t[idx] = v + pos[n * DIM + d];
}

// ---------------------------------------------------------------------------
// LayerNorm, wave-per-row: block = 4 waves = 4 rows. 768 = 64 lanes * 12.
// ---------------------------------------------------------------------------
__global__ __launch_bounds__(256) void lnw_kernel(const float* __restrict__ x,
                                                  const float* __restrict__ g,
                                                  const float* __restrict__ bta,
                                                  ushort* __restrict__ out,
                                                  int rows, int in_stride, int out_stride) {
    int w = threadIdx.x >> 6, l = threadIdx.x & 63;
    int row = blockIdx.x * 4 + w;
    if (row >= rows) return;
    const float* xr = x + (size_t)row * in_stride;
    float4 v[3];
    float s = 0.0f, s2 = 0.0f;
#pragma unroll
    for (int c = 0; c < 3; c++) {
        v[c] = *(const float4*)(xr + c * 256 + l * 4);
        s  += v[c].x + v[c].y + v[c].z + v[c].w;
        s2 += v[c].x * v[c].x + v[c].y * v[c].y + v[c].z * v[c].z + v[c].w * v[c].w;
    }
#pragma unroll
    for (int off = 32; off; off >>= 1) { s += __shfl_xor(s, off); s2 += __shfl_xor(s2, off); }
    float mean = s * (1.0f / DIM);
    float inv = rsqrtf(s2 * (1.0f / DIM) - mean * mean + 1e-6f);
    ushort* orow = out + (size_t)row * out_stride;
#pragma unroll
    for (int c = 0; c < 3; c++) {
        float4 gg = *(const float4*)(g + c * 256 + l * 4);
        float4 bb = *(const float4*)(bta + c * 256 + l * 4);
        ushort4 o4;
        o4.x = f2bf((v[c].x - mean) * inv * gg.x + bb.x);
        o4.y = f2bf((v[c].y - mean) * inv * gg.y + bb.y);
        o4.z = f2bf((v[c].z - mean) * inv * gg.z + bb.z);
        o4.w = f2bf((v[c].w - mean) * inv * gg.w + bb.w);
        *(ushort4*)(orow + c * 256 + l * 4) = o4;
    }
}

// ---------------------------------------------------------------------------
// Bounded transpose (pre-loop: patch_w, head_w). in KxN -> out NxK bf16.
// ---------------------------------------------------------------------------
__global__ __launch_bounds__(256) void transpose_bf16_kernel(const float* __restrict__ in,
                                                             ushort* __restrict__ out,
                                                             int K, int N) {
    __shared__ float tile[32][33];
    int n0 = blockIdx.x * 32, k0 = blockIdx.y * 32;
    int tx = threadIdx.x;
    int ty = threadIdx.y;
    for (int r = ty; r < 32; r += 8) {
        int k = k0 + r, n = n0 + tx;
        tile[r][tx] = (k < K && n < N) ? in[(size_t)k * N + n] : 0.0f;
    }
    __syncthreads();
    for (int r = ty; r < 32; r += 8) {
        int n = n0 + r, k = k0 + tx;
        if (n < N && k < K) out[(size_t)n * K + k] = f2bf(tile[tx][r]);
    }
}

// ---------------------------------------------------------------------------
// Batched per-layer transpose of the 4 weight mats (all dims %32==0).
// tiles: qkv 72x24=1728 | proj 24x24=576 | fc1 96x24=2304 | fc2 24x96=2304
// ---------------------------------------------------------------------------
__global__ __launch_bounds__(256) void transpose4_kernel(
    const float* __restrict__ w0, const float* __restrict__ w1,
    const float* __restrict__ w2, const float* __restrict__ w3,
    ushort* __restrict__ o0, ushort* __restrict__ o1,
    ushort* __restrict__ o2, ushort* __restrict__ o3) {
    __shared__ float tile[32][33];
    int bid = blockIdx.x;
    const float* in; ushort* out; int K, N, nx, tl;
    if (bid < 1728)      { in = w0; out = o0; K = 768;  N = 2304; nx = 72; tl = bid; }
    else if (bid < 2304) { in = w1; out = o1; K = 768;  N = 768;  nx = 24; tl = bid - 1728; }
    else if (bid < 4608) { in = w2; out = o2; K = 768;  N = 3072; nx = 96; tl = bid - 2304; }
    else                 { in = w3; out = o3; K = 3072; N = 768;  nx = 24; tl = bid - 4608; }
    int n0 = (tl % nx) * 32, k0 = (tl / nx) * 32;
    int tx = threadIdx.x, ty = threadIdx.y;
    for (int r = ty; r < 32; r += 8)
        tile[r][tx] = in[(size_t)(k0 + r) * N + n0 + tx];
    __syncthreads();
    for (int r = ty; r < 32; r += 8)
        out[(size_t)(n0 + r) * K + k0 + tx] = f2bf(tile[tx][r]);
}

// ---------------------------------------------------------------------------
// bf16 MFMA GEMM: BMx128x64 tiles (BM=128 or 64), 4 waves, 16x16x32 MFMA.
// XOR-swizzled LDS chunks (conflict-free ds_read_b128), GROUP_M=8 block
// swizzle for L2 locality. Wt is NxK (row n = col n of W).
//
// Round-6: swapped-operand MFMA (mfma(B,A)) -> C fragment is transposed:
// each thread holds 4 CONSECUTIVE COLUMNS of one output row instead of 4
// scattered rows of one column. Epilogue becomes ushort4/float4 vector
// loads+stores (16 instead of 64 scalar ops), which was the diagnosed
// VALUBusy-43%/WRITE-1.9x bottleneck. Results are bitwise identical (same
// per-element dot products).
//  * BM=128 (qkv/fc1, K=768): single-buffer + __syncthreads (lives on
//    cross-block TLP: 32KB LDS -> 5 blocks/CU).
//  * BM=64 (proj/fc2/patch/head): double-buffer + counted vmcnt(6) + raw
//    s_barrier (residency unchanged; cross-barrier pipelining is free).
// ---------------------------------------------------------------------------
template <int BM, int GELU, int RES, int WF32, int WBF16>
__global__ __launch_bounds__(256) void gemm_bf16_mfma(
    const ushort* __restrict__ A, const ushort* __restrict__ Wt,
    const float* __restrict__ bias, const float* __restrict__ res,
    float* __restrict__ Cf, ushort* __restrict__ Cb,
    int M, int N, int K) {
    constexpr int WN = (BM == 128) ? 2 : 4;   // waves along N
    constexpr int FN = (BM == 128) ? 4 : 2;   // 16-col frags per wave
    constexpr int AROWS = BM / 4;             // A rows staged per wave
    constexpr int ABUF = BM * 64;             // shorts per A buffer
    constexpr int BBUF = 128 * 64;            // shorts per B buffer
    constexpr int DBUF = (BM == 64) ? 2 : 1;  // double-buffer only for BM=64
    __shared__ short Asm[DBUF * ABUF];
    __shared__ short Bsm[DBUF * BBUF];
    const int tid = threadIdx.x;
    const int w = tid >> 6, lane = tid & 63;
    const int wm = w / WN, wn = w % WN;

    // GROUP_M=8 swizzled block mapping
    int gX = gridDim.x, gY = gridDim.y;
    int pid = blockIdx.y * gX + blockIdx.x;
    int width = 8 * gX;
    int group = pid / width;
    int first = group * 8;
    int gsz = min(gY - first, 8);
    int by = first + (pid % gsz);
    int bx = (pid % width) / gsz;
    const int m0 = by * BM, n0 = bx * 128;

    floatx4 acc[4][FN] = {};

    // staging: lane -> (row-in-8 = lane>>3, slot = lane&7), global chunk = slot^row
    const int ro = lane >> 3;
    const int sl = lane & 7;
    const int gch = sl ^ ro;
    const ushort* aptr[BM / 32];
    short* alds[BM / 32];
#pragma unroll
    for (int i = 0; i < BM / 32; i++) {
        int r = w * AROWS + i * 8 + ro;
        int gr = min(m0 + r, M - 1);
        aptr[i] = A + (size_t)gr * K + gch * 8;
        alds[i] = Asm + (w * AROWS + i * 8) * 64;
    }
    const ushort* bptr[4];
    short* blds[4];
#pragma unroll
    for (int i = 0; i < 4; i++) {
        int r = w * 32 + i * 8 + ro;
        int gr = min(n0 + r, N - 1);
        bptr[i] = Wt + (size_t)gr * K + gch * 8;
        blds[i] = Bsm + (w * 32 + i * 8) * 64;
    }

    const int fr = lane & 15, quad = lane >> 4;

    auto compute_tile = [&](const short* As, const short* Bs) {
#pragma unroll
        for (int ks = 0; ks < 2; ks++) {
            int soff = (((ks * 4 + quad) ^ (fr & 7)) * 8);
            short8 af[4], bfv[FN];
#pragma unroll
            for (int mt = 0; mt < 4; mt++)
                af[mt] = *(const short8*)&As[(wm * 64 + mt * 16 + fr) * 64 + soff];
#pragma unroll
            for (int nt = 0; nt < FN; nt++)
                bfv[nt] = *(const short8*)&Bs[(wn * (16 * FN) + nt * 16 + fr) * 64 + soff];
            // swapped operands: D = (B,A) -> thread holds row=..+fr, cols=..+quad*4+r
#pragma unroll
            for (int mt = 0; mt < 4; mt++)
#pragma unroll
                for (int nt = 0; nt < FN; nt++)
                    acc[mt][nt] = __builtin_amdgcn_mfma_f32_16x16x32_bf16(bfv[nt], af[mt], acc[mt][nt], 0, 0, 0);
        }
    };

    if constexpr (BM == 64) {
        const int nsteps = K >> 6;
        // prologue: stage tile 0 into buffer 0
#pragma unroll
        for (int i = 0; i < BM / 32; i++) async_copy16(aptr[i], alds[i]);
#pragma unroll
        for (int i = 0; i < 4; i++) async_copy16(bptr[i], blds[i]);
        int cur = 0;
        for (int t = 0; t < nsteps; ++t) {
            if (t + 1 < nsteps) {
                const int nxt = cur ^ 1;
                const int kk = (t + 1) << 6;
#pragma unroll
                for (int i = 0; i < BM / 32; i++) async_copy16(aptr[i] + kk, alds[i] + nxt * ABUF);
#pragma unroll
                for (int i = 0; i < 4; i++) async_copy16(bptr[i] + kk, blds[i] + nxt * BBUF);
                // wait only for the current tile's 6 loads; next tile's stay in flight
                asm volatile("s_waitcnt vmcnt(6)" ::: "memory");
            } else {
                asm volatile("s_waitcnt vmcnt(0)" ::: "memory");
            }
            asm volatile("s_barrier" ::: "memory");
            compute_tile(Asm + cur * ABUF, Bsm + cur * BBUF);
            asm volatile("s_barrier" ::: "memory");
            cur ^= 1;
        }
    } else {
        for (int k0 = 0; k0 < K; k0 += 64) {
#pragma unroll
            for (int i = 0; i < BM / 32; i++) async_copy16(aptr[i] + k0, alds[i]);
#pragma unroll
            for (int i = 0; i < 4; i++) async_copy16(bptr[i] + k0, blds[i]);
            __syncthreads();
            compute_tile(Asm, Bsm);
            __syncthreads();
        }
    }

    // Transposed-fragment epilogue: row = m0+wm*64+mt*16+fr (per-lane),
    // cols = n0+wn*(16*FN)+nt*16+quad*4 .. +3 (4 consecutive, 4-aligned).
    const int colbase = n0 + wn * (16 * FN) + quad * 4;
#pragma unroll
    for (int nt = 0; nt < FN; nt++) {
        int col0 = colbase + nt * 16;
        if (col0 >= N) continue;  // N%4==0 so 4-col groups are all-in or all-out
        float4 bv = *(const float4*)(bias + col0);
#pragma unroll
        for (int mt = 0; mt < 4; mt++) {
            int row = m0 + wm * 64 + mt * 16 + fr;
            if (row >= M) continue;
            float v0 = acc[mt][nt][0] + bv.x;
            float v1 = acc[mt][nt][1] + bv.y;
            float v2 = acc[mt][nt][2] + bv.z;
            float v3 = acc[mt][nt][3] + bv.w;
            if (GELU) {
                v0 = gelu_fast(v0); v1 = gelu_fast(v1);
                v2 = gelu_fast(v2); v3 = gelu_fast(v3);
            }
            if (RES) {
                float4 rv = *(const float4*)(res + (size_t)row * N + col0);
                v0 += rv.x; v1 += rv.y; v2 += rv.z; v3 += rv.w;
            }
            if (WF32) {
                float4 o; o.x = v0; o.y = v1; o.z = v2; o.w = v3;
                *(float4*)(Cf + (size_t)row * N + col0) = o;
            }
            if (WBF16) {
                ushort4 o;
                o.x = f2bf(v0); o.y = f2bf(v1); o.z = f2bf(v2); o.w = f2bf(v3);
                *(ushort4*)(Cb + (size_t)row * N + col0) = o;
            }
        }
    }
}

// ---------------------------------------------------------------------------
// MFMA attention (round-3 version, unchanged).
// ---------------------------------------------------------------------------
__global__ __launch_bounds__(256, 2) void attn_kernel(const ushort* __restrict__ qkvb,
                                                      const float* __restrict__ mask,
                                                      ushort* __restrict__ o) {
    const int h = blockIdx.x, b = blockIdx.y;
    const int tid = threadIdx.x;
    __shared__ ushort Vfrag[7 * 4 * 64 * 8];
    __shared__ ushort Pfrag[4 * 7 * 64 * 8];

    {
        uint4 z = {0, 0, 0, 0};
        uint4* v4 = (uint4*)Vfrag;
        uint4* p4 = (uint4*)Pfrag;
        for (int i = tid; i < 1792; i += 256) { v4[i] = z; p4[i] = z; }
    }
    __syncthreads();

    for (int pass = 0; pass < 25; pass++) {
        int j = pass * 8 + (tid >> 5);
        if (j <= 196) {
            int d0 = (tid & 31) * 2;
            unsigned int val = *(const unsigned int*)(qkvb + ((size_t)(b * N_TOK + j) * 3 + 2) * DIM + h * HD + d0);
            int kt = j >> 5, dt = d0 >> 4;
            int lane = ((j & 31) >> 3) * 16 + (d0 & 15);
            int jj = j & 7;
            int base = (kt * 4 + dt) * 512 + lane * 8 + jj;
            Vfrag[base] = (ushort)(val & 0xffffu);
            Vfrag[base + 8] = (ushort)(val >> 16);
        }
    }
    __syncthreads();

    const int w = tid >> 6, l = tid & 63;
    const int q = l >> 4, fr = l & 15;
    ushort* Pw = Pfrag + w * 3584;
    const float scale = 0.125f;

    for (int qt = w; qt < 13; qt += 4) {
        int qrow = min(qt * 16 + fr, 196);
        const ushort* qptr = qkvb + ((size_t)(b * N_TOK + qrow) * 3 + 0) * DIM + h * HD + q * 8;
        short8 aq0 = *(const short8*)qptr;
        short8 aq1 = *(const short8*)(qptr + 32);

        floatx4 sacc[13];
#pragma unroll
        for (int nt = 0; nt < 13; nt++) {
            int krow = min(nt * 16 + fr, 196);
            const ushort* kptr = qkvb + ((size_t)(b * N_TOK + krow) * 3 + 1) * DIM + h * HD + q * 8;
            short8 kb0 = *(const short8*)kptr;
            short8 kb1 = *(const short8*)(kptr + 32);
            floatx4 acc = {};
            acc = __builtin_amdgcn_mfma_f32_16x16x32_bf16(aq0, kb0, acc, 0, 0, 0);
            acc = __builtin_amdgcn_mfma_f32_16x16x32_bf16(aq1, kb1, acc, 0, 0, 0);
            sacc[nt] = acc;
        }

        float mx[4] = {-1e30f, -1e30f, -1e30f, -1e30f};
#pragma unroll
        for (int nt = 0; nt < 13; nt++) {
            int jcol = nt * 16 + fr;
#pragma unroll
            for (int r = 0; r < 4; r++) {
                int irow = min(qt * 16 + q * 4 + r, 196);
                float s;
                if (jcol <= 196) s = sacc[nt][r] * scale * mask[irow * N_TOK + jcol];
                else s = -1e30f;
                sacc[nt][r] = s;
                mx[r] = fmaxf(mx[r], s);
            }
        }
#pragma unroll
        for (int r = 0; r < 4; r++) {
            mx[r] = fmaxf(mx[r], __shfl_xor(mx[r], 1));
            mx[r] = fmaxf(mx[r], __shfl_xor(mx[r], 2));
            mx[r] = fmaxf(mx[r], __shfl_xor(mx[r], 4));
            mx[r] = fmaxf(mx[r], __shfl_xor(mx[r], 8));
        }

        float sum[4] = {0, 0, 0, 0};
#pragma unroll
        for (int nt = 0; nt < 13; nt++) {
            int kt = nt >> 1;
            int lpbase = ((nt & 1) * 2 + ((l & 8) >> 3)) * 16;
#pragma unroll
            for (int r = 0; r < 4; r++) {
                float e = __expf(sacc[nt][r] - mx[r]);
                sum[r] += e;
                int lp = (q * 4 + r) + lpbase;
                Pw[kt * 512 + lp * 8 + (l & 7)] = f2bf(e);
            }
        }
#pragma unroll
        for (int r = 0; r < 4; r++) {
            sum[r] += __shfl_xor(sum[r], 1);
            sum[r] += __shfl_xor(sum[r], 2);
            sum[r] += __shfl_xor(sum[r], 4);
            sum[r] += __shfl_xor(sum[r], 8);
        }

        floatx4 oacc[4] = {};
#pragma unroll
        for (int kt = 0; kt < 7; kt++) {
            short8 pa = *(const short8*)&Pw[kt * 512 + l * 8];
#pragma unroll
            for (int dt = 0; dt < 4; dt++) {
                short8 vb = *(const short8*)&Vfrag[(kt * 4 + dt) * 512 + l * 8];
                oacc[dt] = __builtin_amdgcn_mfma_f32_16x16x32_bf16(pa, vb, oacc[dt], 0, 0, 0);
            }
        }

        float inv[4];
#pragma unroll
        for (int r = 0; r < 4; r++) inv[r] = 1.0f / sum[r];
#pragma unroll
        for (int dt = 0; dt < 4; dt++) {
#pragma unroll
            for (int r = 0; r < 4; r++) {
                int irow = qt * 16 + q * 4 + r;
                if (irow <= 196)
                    o[((size_t)(b * N_TOK + irow)) * DIM + h * HD + dt * 16 + fr] = f2bf(oacc[dt][r] * inv[r]);
            }
        }
    }
}

// ---------------------------------------------------------------------------
extern "C" void kernel_launch(void* const* d_in, const int* in_sizes, int n_in,
                              void* d_out, int out_size, void* d_ws, size_t ws_size,
                              hipStream_t stream) {
    const float* x       = (const float*)d_in[0];
    const float* cp_mask = (const float*)d_in[1];
    const float* patch_w = (const float*)d_in[2];
    const float* patch_b = (const float*)d_in[3];
    const float* cls_tok = (const float*)d_in[4];
    const float* pos_emb = (const float*)d_in[5];
    const float* ln1_g   = (const float*)d_in[6];
    const float* ln1_b   = (const float*)d_in[7];
    const float* qkv_w   = (const float*)d_in[8];
    const float* qkv_b   = (const float*)d_in[9];
    const float* proj_w  = (const float*)d_in[10];
    const float* proj_b  = (const float*)d_in[11];
    const float* ln2_g   = (const float*)d_in[12];
    const float* ln2_b   = (const float*)d_in[13];
    const float* fc1_w   = (const float*)d_in[14];
    const float* fc1_b   = (const float*)d_in[15];
    const float* fc2_w   = (const float*)d_in[16];
    const float* fc2_b   = (const float*)d_in[17];
    const float* normf_g = (const float*)d_in[18];
    const float* normf_b = (const float*)d_in[19];
    const float* head_w  = (const float*)d_in[20];
    const float* head_b  = (const float*)d_in[21];
    float* out = (float*)d_out;

    const int M = BATCH * N_TOK;  // 6304
    char* p = (char*)d_ws;
    auto alloc = [&](size_t bytes) { char* r = p; p += (bytes + 255) & ~(size_t)255; return r; };
    float*  t         = (float*)alloc((size_t)M * DIM * 4);
    float*  patchout  = (float*)alloc((size_t)BATCH * NPATCH * DIM * 4);
    ushort* h_bf      = (ushort*)alloc((size_t)M * DIM * 2);
    ushort* qkv_bf    = (ushort*)alloc((size_t)M * 3 * DIM * 2);
    ushort* o_bf      = (ushort*)alloc((size_t)M * DIM * 2);
    ushort* hidden_bf = (ushort*)alloc((size_t)M * MLP_DIM * 2);
    ushort* pooled_bf = (ushort*)alloc((size_t)BATCH * DIM * 2);
    ushort* wq_t      = (ushort*)alloc((size_t)3 * DIM * DIM * 2);
    ushort* wp_t      = (ushort*)alloc((size_t)DIM * DIM * 2);
    ushort* w1_t      = (ushort*)alloc((size_t)MLP_DIM * DIM * 2);
    ushort* w2_t      = (ushort*)alloc((size_t)DIM * MLP_DIM * 2);
    ushort* wpt       = (ushort*)alloc((size_t)DIM * DIM * 2);
    ushort* wht       = (ushort*)alloc((size_t)NCLS * DIM * 2);

    const dim3 tb(32, 8);

    transpose_bf16_kernel<<<dim3(24, 24), tb, 0, stream>>>(patch_w, wpt, DIM, DIM);
    transpose_bf16_kernel<<<dim3(32, 24), tb, 0, stream>>>(head_w, wht, DIM, NCLS);
    {
        int total = BATCH * NPATCH * DIM;
        im2col_kernel<<<(total + 255) / 256, 256, 0, stream>>>(x, h_bf);
        gemm_bf16_mfma<64, 0, 0, 1, 0><<<dim3(6, 98), 256, 0, stream>>>(
            h_bf, wpt, patch_b, nullptr, patchout, nullptr, BATCH * NPATCH, DIM, DIM);
        int total2 = M * DIM;
        assemble_kernel<<<(total2 + 255) / 256, 256, 0, stream>>>(patchout, cls_tok, pos_emb, t);
    }

    for (int l = 0; l < DEPTH; l++) {
        transpose4_kernel<<<6912, tb, 0, stream>>>(
            qkv_w + (size_t)l * DIM * 3 * DIM, proj_w + (size_t)l * DIM * DIM,
            fc1_w + (size_t)l * DIM * MLP_DIM, fc2_w + (size_t)l * MLP_DIM * DIM,
            wq_t, wp_t, w1_t, w2_t);

        lnw_kernel<<<M / 4, 256, 0, stream>>>(t, ln1_g + l * DIM, ln1_b + l * DIM, h_bf, M, DIM, DIM);

        gemm_bf16_mfma<128, 0, 0, 0, 1><<<dim3(18, 50), 256, 0, stream>>>(
            h_bf, wq_t, qkv_b + (size_t)l * 3 * DIM, nullptr, nullptr, qkv_bf, M, 3 * DIM, DIM);

        attn_kernel<<<dim3(HEADS, BATCH), 256, 0, stream>>>(qkv_bf, cp_mask, o_bf);

        gemm_bf16_mfma<64, 0, 1, 1, 0><<<dim3(6, 99), 256, 0, stream>>>(
            o_bf, wp_t, proj_b + (size_t)l * DIM, t, t, nullptr, M, DIM, DIM);

        lnw_kernel<<<M / 4, 256, 0, stream>>>(t, ln2_g + l * DIM, ln2_b + l * DIM, h_bf, M, DIM, DIM);

        gemm_bf16_mfma<128, 1, 0, 0, 1><<<dim3(24, 50), 256, 0, stream>>>(
            h_bf, w1_t, fc1_b + (size_t)l * MLP_DIM, nullptr, nullptr, hidden_bf, M, MLP_DIM, DIM);

        gemm_bf16_mfma<64, 0, 1, 1, 0><<<dim3(6, 99), 256, 0, stream>>>(
            hidden_bf, w2_t, fc2_b + (size_t)l * DIM, t, t, nullptr, M, DIM, MLP_DIM);
    }

    lnw_kernel<<<8, 256, 0, stream>>>(t, normf_g, normf_b, pooled_bf, BATCH, N_TOK * DIM, DIM);
    gemm_bf16_mfma<64, 0, 0, 1, 0><<<dim3(8, 1), 256, 0, stream>>>(
        pooled_bf, wht, head_b, nullptr, out, nullptr, BATCH, NCLS, DIM);
}